// Round 8
// baseline (264.066 us; speedup 1.0000x reference)
//
#include <hip/hip_runtime.h>
#include <hip/hip_bf16.h>
#include <hip/hip_fp16.h>

#define DEVINL __device__ __forceinline__

typedef __attribute__((ext_vector_type(4))) float    f32x4;
typedef __attribute__((ext_vector_type(8))) short    s16x8;
typedef __attribute__((ext_vector_type(4))) short    s16x4;
typedef __attribute__((ext_vector_type(8))) __bf16   bf16x8;
typedef __attribute__((ext_vector_type(8))) _Float16 f16x8;
typedef __attribute__((ext_vector_type(4))) unsigned u32x4;

typedef __attribute__((address_space(1))) unsigned int gu32_t;
typedef __attribute__((address_space(3))) unsigned int lu32_t;
#define GLL16(g, l) \
  __builtin_amdgcn_global_load_lds((const gu32_t*)(g), (lu32_t*)(l), 16, 0, 0)

// Problem constants
#define BB 2
#define TT 2048
#define CC 1024
#define NHH 16
#define HSS 64
#define LOG2E 1.44269504f

DEVINL unsigned short f2bf(float f) {
  unsigned u = __builtin_bit_cast(unsigned, f);
  unsigned rnd = 0x7FFFu + ((u >> 16) & 1u);
  return (unsigned short)((u + rnd) >> 16);
}
DEVINL unsigned short f2h(float f) {
  _Float16 h = (_Float16)f;
  return __builtin_bit_cast(unsigned short, h);
}
DEVINL unsigned pkrtz(float a, float b) {
  auto h = __builtin_amdgcn_cvt_pkrtz(a, b);  // __fp16 ext_vector(2)
  return __builtin_bit_cast(unsigned, h);
}
DEVINL float ex2(float x) { return __builtin_amdgcn_exp2f(x); }

DEVINL f32x4 mfma_bf16_16x16x32(s16x8 a, s16x8 b, f32x4 c) {
  return __builtin_amdgcn_mfma_f32_16x16x32_bf16(
      __builtin_bit_cast(bf16x8, a), __builtin_bit_cast(bf16x8, b), c, 0, 0, 0);
}
DEVINL f32x4 mfma_f16_16x16x32(s16x8 a, s16x8 b, f32x4 c) {
  return __builtin_amdgcn_mfma_f32_16x16x32_f16(
      __builtin_bit_cast(f16x8, a), __builtin_bit_cast(f16x8, b), c, 0, 0, 0);
}

// ---------------- fp32 -> bf16 convert (x) ----------------
__global__ void cvt_kernel(const float* __restrict__ src,
                           unsigned short* __restrict__ dst, int n) {
  const int i = (blockIdx.x * blockDim.x + threadIdx.x) * 4;
  if (i >= n) return;
  const float4 v = *(const float4*)(src + i);
  s16x4 o;
  o[0] = (short)f2bf(v.x);
  o[1] = (short)f2bf(v.y);
  o[2] = (short)f2bf(v.z);
  o[3] = (short)f2bf(v.w);
  *(s16x4*)(dst + i) = o;
}

// ---------------- fused fp32->bf16 for the 3 weight matrices ------------
__global__ void cvtw_kernel(const float* __restrict__ w1,
                            const float* __restrict__ vw,
                            const float* __restrict__ pw,
                            unsigned short* __restrict__ dst) {
  const int i = blockIdx.x * blockDim.x + threadIdx.x;  // per float4
  const int NW4 = (CC * CC) / 4;
  const float* src;
  int j;
  if (i < NW4)          { src = w1; j = i; }
  else if (i < 2 * NW4) { src = vw; j = i - NW4; }
  else                  { src = pw; j = i - 2 * NW4; }
  const float4 v = *(const float4*)(src + (size_t)j * 4);
  s16x4 o;
  o[0] = (short)f2bf(v.x);
  o[1] = (short)f2bf(v.y);
  o[2] = (short)f2bf(v.z);
  o[3] = (short)f2bf(v.w);
  *(s16x4*)(dst + (size_t)i * 4) = o;
}

// -------- w2 [64][2048] -> w2t bf16 [2048][64] x log2e; b2s = b2 x log2e ---
__global__ void w2t_kernel(const float* __restrict__ w2,
                           unsigned short* __restrict__ w2t,
                           const float* __restrict__ b2,
                           float* __restrict__ b2s) {
  const int idx = blockIdx.x * blockDim.x + threadIdx.x;  // 131072
  const int h = idx >> 11, s = idx & 2047;
  w2t[s * 64 + h] = f2bf(w2[idx] * LOG2E);
  if (idx < TT) b2s[idx] = b2[idx] * LOG2E;
}

// ---------------- GEMM, 64x128 tile, global_load_lds staging -----------
// MODE 0: fused hv. bn<8 -> h path (relu, bf16 [M][N]); bn>=8 -> v path
//         (fp16 scattered in PV-fragment slot order).
// MODE 2: proj path, fp32 out [M][N].
template <int MODE>
__global__ __launch_bounds__(256) void gemm64_kernel(
    const unsigned short* __restrict__ A,    // bf16 [M][K]
    const unsigned short* __restrict__ B0,   // bf16 [N][K]
    const float* __restrict__ bias0,
    const unsigned short* __restrict__ B1,
    const float* __restrict__ bias1,
    unsigned short* __restrict__ outh,
    unsigned short* __restrict__ outv,
    float* __restrict__ outf) {
  constexpr int K = CC, N = CC;
  __shared__ unsigned short As[64 * 32];    // linear (global_load_lds dest)
  __shared__ unsigned short Bs[128 * 32];
  const int tid = threadIdx.x;
  const int lane = tid & 63;
  const int wid = tid >> 6;
  const int g = lane >> 4, r = lane & 15;
  const int wm = (wid & 1) * 32;
  const int wn = (wid >> 1) * 64;
  const int bm = blockIdx.y;
  int bn = blockIdx.x;
  const unsigned short* Bt = B0;
  const float* bias = bias0;
  bool isv = false;
  if (MODE == 0 && bn >= 8) { isv = true; bn -= 8; Bt = B1; bias = bias1; }

  // staging geometry: 16B/lane, 64 rows per shot, 4 colsegs/row
  const int srow = wid * 16 + (lane >> 2);   // 0..63
  const int scol = (lane & 3) * 8;
  const unsigned short* Ag = A + (size_t)(bm * 64 + srow) * K + scol;
  const unsigned short* Bg = Bt + (size_t)(bn * 128 + srow) * K + scol;
  unsigned short* lA0 = &As[wid * 512];
  unsigned short* lB0 = &Bs[wid * 512];
  unsigned short* lB1 = &Bs[2048 + wid * 512];

  f32x4 acc[2][4] = {};
  for (int k0 = 0; k0 < K; k0 += 32) {
    __syncthreads();  // prev compute done before overwrite
    GLL16(Ag + k0, lA0);
    GLL16(Bg + k0, lB0);
    GLL16(Bg + (size_t)64 * K + k0, lB1);
    __syncthreads();  // compiler drains vmcnt here
    s16x8 af[2], bf[4];
#pragma unroll
    for (int mi = 0; mi < 2; ++mi)
      af[mi] = *(const s16x8*)&As[(wm + mi * 16 + r) * 32 + g * 8];
#pragma unroll
    for (int ni = 0; ni < 4; ++ni)
      bf[ni] = *(const s16x8*)&Bs[(wn + ni * 16 + r) * 32 + g * 8];
#pragma unroll
    for (int mi = 0; mi < 2; ++mi)
#pragma unroll
      for (int ni = 0; ni < 4; ++ni)
        acc[mi][ni] = mfma_bf16_16x16x32(af[mi], bf[ni], acc[mi][ni]);
  }

  // Epilogue. D frag: col = r (n), rows = 4*g + r2 (m).
  const int mrow0 = bm * 64 + wm + 4 * g;
  const int ncol0 = bn * 128 + wn + r;
#pragma unroll
  for (int mi = 0; mi < 2; ++mi) {
#pragma unroll
    for (int ni = 0; ni < 4; ++ni) {
      const int n = ncol0 + ni * 16;
      const float bv = bias[n];
      const int m0 = mrow0 + mi * 16;
      if (MODE == 2) {
#pragma unroll
        for (int r2 = 0; r2 < 4; ++r2)
          outf[(size_t)(m0 + r2) * N + n] = acc[mi][ni][r2] + bv;
      } else if (!isv) {
#pragma unroll
        for (int r2 = 0; r2 < 4; ++r2) {
          float v = acc[mi][ni][r2] + bv;
          v = fmaxf(v, 0.0f);
          outh[(size_t)(m0 + r2) * N + n] = f2bf(v);
        }
      } else {
        // v scattered in PV A-frag slot order:
        // addr = bh*131072 + hs*2048 + (t>>5)*32 + ((t>>2)&3)*8 + ((t>>4)&1)*4
        s16x4 o;
#pragma unroll
        for (int r2 = 0; r2 < 4; ++r2)
          o[r2] = (short)f2h(acc[mi][ni][r2] + bv);
        const int tloc = m0 & 2047;
        const size_t dst =
            (size_t)((m0 >> 11) * 16 + (n >> 6)) * (64 * 2048)
            + (size_t)(n & 63) * 2048
            + (size_t)((tloc >> 5) * 32 + ((tloc >> 2) & 3) * 8
                       + ((tloc >> 4) & 1) * 4);
        *(s16x4*)(outv + dst) = o;
      }
    }
  }
}

// ---------------- fused synthesizer attention, v3 ----------------
// Block = 64 q-rows (4 waves x 16), grid bh(32) x qb(32) = 1024 blocks,
// zero LDS -> 4 blocks/CU, all co-resident. Main loop over 64-wide
// s-superblocks strictly below the diagonal: branch-free, no masks.
// Softmax with fixed max=0 is exact (logits tiny); exp2 with w2t,b2
// pre-scaled by log2e; P packed via cvt_pkrtz into K=32 f16 PV MFMAs
// whose A operand (v) is pre-scattered in matching slot order.
__global__ __launch_bounds__(256, 4) void attn_kernel(
    const unsigned short* __restrict__ rh,   // bf16 [B*T][C] relu(h)
    const unsigned short* __restrict__ vt,   // fp16 slot-ordered v^T
    const unsigned short* __restrict__ w2t,  // bf16 [T][64] x log2e
    const float* __restrict__ b2s,           // [T] b2 x log2e
    unsigned short* __restrict__ yb) {       // bf16 [B*T][C]
  const int tid = threadIdx.x;
  const int lane = tid & 63;
  const int wid = tid >> 6;              // 0..3
  const int g = lane >> 4, r = lane & 15;
  const int bh = blockIdx.x & 31;
  const int slot = blockIdx.x >> 5;      // 0..31
  // per-CU balanced: heavy (31..16) first, then light (0..15)
  const int qb = (slot < 16) ? (31 - slot) : (slot - 16);
  const int b = bh >> 4, nh = bh & 15;
  const int t0 = qb * 64;
  const int t = t0 + wid * 16 + r;       // this lane's q row

  // Q fragment (B-operand of S^T = w2t x rh)
  const unsigned short* qbase =
      rh + (size_t)(b * TT + t) * CC + nh * 64 + g * 8;
  const s16x8 qf0 = *(const s16x8*)(qbase);
  const s16x8 qf1 = *(const s16x8*)(qbase + 32);

  f32x4 yacc[4] = {};                    // [f] -> hs = f*16 + 4g + r2
  float lsum = 0.f;

  const unsigned short* wbase = w2t + r * 64 + g * 8;
  const unsigned short* vbase =
      vt + (size_t)bh * (64 * 2048) + (size_t)r * 2048 + g * 8;
  const float* bbase = b2s + 4 * g;

  // -------- main loop: qb full 64-s superblocks, unmasked --------
  for (int j = 0; j < qb; ++j) {
    unsigned pk[8];
#pragma unroll
    for (int sub = 0; sub < 4; ++sub) {
      const unsigned short* wp = wbase + j * 4096 + sub * 1024;
      const s16x8 af0 = *(const s16x8*)(wp);
      const s16x8 af1 = *(const s16x8*)(wp + 32);
      f32x4 s = *(const f32x4*)(bbase + j * 64 + sub * 16);  // C-init = b2s
      s = mfma_bf16_16x16x32(af0, qf0, s);
      s = mfma_bf16_16x16x32(af1, qf1, s);
      const float p0 = ex2(s[0]), p1 = ex2(s[1]);
      const float p2 = ex2(s[2]), p3 = ex2(s[3]);
      lsum += (p0 + p1) + (p2 + p3);
      pk[sub * 2 + 0] = pkrtz(p0, p1);
      pk[sub * 2 + 1] = pkrtz(p2, p3);
    }
#pragma unroll
    for (int grp = 0; grp < 2; ++grp) {
      u32x4 pw = {pk[grp * 4 + 0], pk[grp * 4 + 1],
                  pk[grp * 4 + 2], pk[grp * 4 + 3]};
      const s16x8 pb = __builtin_bit_cast(s16x8, pw);
      const int so = (2 * j + grp) * 32;
#pragma unroll
      for (int f = 0; f < 4; ++f) {
        const s16x8 vf = *(const s16x8*)(vbase + (size_t)f * 32768 + so);
        yacc[f] = mfma_f16_16x16x32(vf, pb, yacc[f]);
      }
    }
  }

  // -------- diagonal tail: subs j=0..wid at s = t0+16j, masked --------
#pragma unroll
  for (int jj = 0; jj < 2; ++jj) {
    if (jj > (wid >> 1)) break;  // wave-uniform
    unsigned pk[4] = {0u, 0u, 0u, 0u};
#pragma unroll
    for (int h = 0; h < 2; ++h) {
      const int sub = 2 * jj + h;
      if (sub > wid) break;      // wave-uniform
      const int sbb = t0 + sub * 16;
      const unsigned short* wp = wbase + (size_t)sbb * 64;
      const s16x8 af0 = *(const s16x8*)(wp);
      const s16x8 af1 = *(const s16x8*)(wp + 32);
      f32x4 s = *(const f32x4*)(b2s + sbb + 4 * g);
      s = mfma_bf16_16x16x32(af0, qf0, s);
      s = mfma_bf16_16x16x32(af1, qf1, s);
      float p[4];
#pragma unroll
      for (int r2 = 0; r2 < 4; ++r2) {
        const int sc = sbb + 4 * g + r2;
        p[r2] = (sc <= t) ? ex2(s[r2]) : 0.f;
      }
      lsum += (p[0] + p[1]) + (p[2] + p[3]);
      pk[h * 2 + 0] = pkrtz(p[0], p[1]);
      pk[h * 2 + 1] = pkrtz(p[2], p[3]);
    }
    u32x4 pw = {pk[0], pk[1], pk[2], pk[3]};
    const s16x8 pb = __builtin_bit_cast(s16x8, pw);
    const int so = (2 * qb + jj) * 32;
#pragma unroll
    for (int f = 0; f < 4; ++f) {
      const s16x8 vf = *(const s16x8*)(vbase + (size_t)f * 32768 + so);
      yacc[f] = mfma_f16_16x16x32(vf, pb, yacc[f]);
    }
  }

  // -------- row sum + write --------
  lsum += __shfl_xor(lsum, 16);
  lsum += __shfl_xor(lsum, 32);
  const float inv = 1.0f / lsum;
  unsigned short* ob = yb + (size_t)(b * TT + t) * CC + nh * 64 + 4 * g;
#pragma unroll
  for (int f = 0; f < 4; ++f) {
    s16x4 o;
#pragma unroll
    for (int r2 = 0; r2 < 4; ++r2) o[r2] = (short)f2bf(yacc[f][r2] * inv);
    *(s16x4*)(ob + f * 16) = o;
  }
}

extern "C" void kernel_launch(void* const* d_in, const int* in_sizes, int n_in,
                              void* d_out, int out_size, void* d_ws,
                              size_t ws_size, hipStream_t stream) {
  const float* x      = (const float*)d_in[0];
  const float* w1_w   = (const float*)d_in[1];
  const float* w1_b   = (const float*)d_in[2];
  const float* w2     = (const float*)d_in[3];
  const float* b2     = (const float*)d_in[4];
  const float* v_w    = (const float*)d_in[5];
  const float* v_b    = (const float*)d_in[6];
  const float* proj_w = (const float*)d_in[7];
  const float* proj_b = (const float*)d_in[8];

  unsigned short* ws = (unsigned short*)d_ws;
  const size_t NX = (size_t)BB * TT * CC;  // 4194304
  const size_t NW = (size_t)CC * CC;       // 1048576
  unsigned short* xb  = ws;
  unsigned short* hb  = xb + NX;
  unsigned short* yb  = hb + NX;
  unsigned short* vt  = yb + NX;   // fp16 v, PV slot order
  unsigned short* w1b = vt + NX;   // w1b, vwb, pwb contiguous (cvtw)
  unsigned short* vwb = w1b + NW;
  unsigned short* pwb = vwb + NW;
  unsigned short* w2t = pwb + NW;  // bf16 [2048][64] x log2e
  float* b2s = (float*)(w2t + (size_t)TT * 64);  // [2048]

  cvt_kernel<<<4096, 256, 0, stream>>>(x, xb, (int)NX);
  cvtw_kernel<<<3072, 256, 0, stream>>>(w1_w, v_w, proj_w, w1b);
  w2t_kernel<<<512, 256, 0, stream>>>(w2, w2t, b2, b2s);

  gemm64_kernel<0><<<dim3(16, 64), 256, 0, stream>>>(
      xb, w1b, w1_b, vwb, v_b, hb, vt, nullptr);
  attn_kernel<<<1024, 256, 0, stream>>>(hb, vt, w2t, b2s, yb);
  gemm64_kernel<2><<<dim3(8, 64), 256, 0, stream>>>(
      yb, pwb, proj_b, nullptr, nullptr, nullptr, nullptr, (float*)d_out);
}

// Round 12
// 184.332 us; speedup vs baseline: 1.4326x; 1.4326x over previous
//
#include <hip/hip_runtime.h>
#include <hip/hip_bf16.h>
#include <hip/hip_fp16.h>

#define DEVINL __device__ __forceinline__

typedef __attribute__((ext_vector_type(4))) float    f32x4;
typedef __attribute__((ext_vector_type(8))) short    s16x8;
typedef __attribute__((ext_vector_type(4))) short    s16x4;
typedef __attribute__((ext_vector_type(8))) __bf16   bf16x8;
typedef __attribute__((ext_vector_type(8))) _Float16 f16x8;
typedef __attribute__((ext_vector_type(4))) unsigned u32x4;

typedef __attribute__((address_space(1))) unsigned int gu32_t;
typedef __attribute__((address_space(3))) unsigned int lu32_t;
#define GLL16(g, l) \
  __builtin_amdgcn_global_load_lds((const gu32_t*)(g), (lu32_t*)(l), 16, 0, 0)

// Problem constants
#define BB 2
#define TT 2048
#define CC 1024
#define NHH 16
#define HSS 64
#define LOG2E 1.44269504f

DEVINL unsigned short f2bf(float f) {
  unsigned u = __builtin_bit_cast(unsigned, f);
  unsigned rnd = 0x7FFFu + ((u >> 16) & 1u);
  return (unsigned short)((u + rnd) >> 16);
}
DEVINL unsigned short f2h(float f) {
  _Float16 h = (_Float16)f;
  return __builtin_bit_cast(unsigned short, h);
}
DEVINL unsigned pkrtz(float a, float b) {
  auto h = __builtin_amdgcn_cvt_pkrtz(a, b);  // __fp16 ext_vector(2)
  return __builtin_bit_cast(unsigned, h);
}
DEVINL float ex2(float x) { return __builtin_amdgcn_exp2f(x); }

DEVINL f32x4 mfma_bf16_16x16x32(s16x8 a, s16x8 b, f32x4 c) {
  return __builtin_amdgcn_mfma_f32_16x16x32_bf16(
      __builtin_bit_cast(bf16x8, a), __builtin_bit_cast(bf16x8, b), c, 0, 0, 0);
}
DEVINL f32x4 mfma_f16_16x16x32(s16x8 a, s16x8 b, f32x4 c) {
  return __builtin_amdgcn_mfma_f32_16x16x32_f16(
      __builtin_bit_cast(f16x8, a), __builtin_bit_cast(f16x8, b), c, 0, 0, 0);
}

// ---------------- fp32 -> bf16 convert (x) ----------------
__global__ void cvt_kernel(const float* __restrict__ src,
                           unsigned short* __restrict__ dst, int n) {
  const int i = (blockIdx.x * blockDim.x + threadIdx.x) * 4;
  if (i >= n) return;
  const float4 v = *(const float4*)(src + i);
  s16x4 o;
  o[0] = (short)f2bf(v.x);
  o[1] = (short)f2bf(v.y);
  o[2] = (short)f2bf(v.z);
  o[3] = (short)f2bf(v.w);
  *(s16x4*)(dst + i) = o;
}

// ---------------- fused fp32->bf16 for the 3 weight matrices ------------
__global__ void cvtw_kernel(const float* __restrict__ w1,
                            const float* __restrict__ vw,
                            const float* __restrict__ pw,
                            unsigned short* __restrict__ dst) {
  const int i = blockIdx.x * blockDim.x + threadIdx.x;  // per float4
  const int NW4 = (CC * CC) / 4;
  const float* src;
  int j;
  if (i < NW4)          { src = w1; j = i; }
  else if (i < 2 * NW4) { src = vw; j = i - NW4; }
  else                  { src = pw; j = i - 2 * NW4; }
  const float4 v = *(const float4*)(src + (size_t)j * 4);
  s16x4 o;
  o[0] = (short)f2bf(v.x);
  o[1] = (short)f2bf(v.y);
  o[2] = (short)f2bf(v.z);
  o[3] = (short)f2bf(v.w);
  *(s16x4*)(dst + (size_t)i * 4) = o;
}

// -------- w2 [64][2048] -> w2t bf16 [2048][64] x log2e; b2s = b2 x log2e ---
__global__ void w2t_kernel(const float* __restrict__ w2,
                           unsigned short* __restrict__ w2t,
                           const float* __restrict__ b2,
                           float* __restrict__ b2s) {
  const int idx = blockIdx.x * blockDim.x + threadIdx.x;  // 131072
  const int h = idx >> 11, s = idx & 2047;
  w2t[s * 64 + h] = f2bf(w2[idx] * LOG2E);
  if (idx < TT) b2s[idx] = b2[idx] * LOG2E;
}

// ---------------- GEMM, 64x128 tile, global_load_lds staging -----------
// MODE 0: fused hv. bn<8 -> h path (relu, bf16 [M][N]); bn>=8 -> v path
//         (fp16 scattered in PV-fragment slot order).
// MODE 2: proj path, fp32 out [M][N].
template <int MODE>
__global__ __launch_bounds__(256) void gemm64_kernel(
    const unsigned short* __restrict__ A,    // bf16 [M][K]
    const unsigned short* __restrict__ B0,   // bf16 [N][K]
    const float* __restrict__ bias0,
    const unsigned short* __restrict__ B1,
    const float* __restrict__ bias1,
    unsigned short* __restrict__ outh,
    unsigned short* __restrict__ outv,
    float* __restrict__ outf) {
  constexpr int K = CC, N = CC;
  __shared__ unsigned short As[64 * 32];    // linear (global_load_lds dest)
  __shared__ unsigned short Bs[128 * 32];
  const int tid = threadIdx.x;
  const int lane = tid & 63;
  const int wid = tid >> 6;
  const int g = lane >> 4, r = lane & 15;
  const int wm = (wid & 1) * 32;
  const int wn = (wid >> 1) * 64;
  const int bm = blockIdx.y;
  int bn = blockIdx.x;
  const unsigned short* Bt = B0;
  const float* bias = bias0;
  bool isv = false;
  if (MODE == 0 && bn >= 8) { isv = true; bn -= 8; Bt = B1; bias = bias1; }

  // staging geometry: 16B/lane, 64 rows per shot, 4 colsegs/row
  const int srow = wid * 16 + (lane >> 2);   // 0..63
  const int scol = (lane & 3) * 8;
  const unsigned short* Ag = A + (size_t)(bm * 64 + srow) * K + scol;
  const unsigned short* Bg = Bt + (size_t)(bn * 128 + srow) * K + scol;
  unsigned short* lA0 = &As[wid * 512];
  unsigned short* lB0 = &Bs[wid * 512];
  unsigned short* lB1 = &Bs[2048 + wid * 512];

  f32x4 acc[2][4] = {};
  for (int k0 = 0; k0 < K; k0 += 32) {
    __syncthreads();  // prev compute done before overwrite
    GLL16(Ag + k0, lA0);
    GLL16(Bg + k0, lB0);
    GLL16(Bg + (size_t)64 * K + k0, lB1);
    __syncthreads();  // compiler drains vmcnt here
    s16x8 af[2], bf[4];
#pragma unroll
    for (int mi = 0; mi < 2; ++mi)
      af[mi] = *(const s16x8*)&As[(wm + mi * 16 + r) * 32 + g * 8];
#pragma unroll
    for (int ni = 0; ni < 4; ++ni)
      bf[ni] = *(const s16x8*)&Bs[(wn + ni * 16 + r) * 32 + g * 8];
#pragma unroll
    for (int mi = 0; mi < 2; ++mi)
#pragma unroll
      for (int ni = 0; ni < 4; ++ni)
        acc[mi][ni] = mfma_bf16_16x16x32(af[mi], bf[ni], acc[mi][ni]);
  }

  // Epilogue. D frag: col = r (n), rows = 4*g + r2 (m).
  const int mrow0 = bm * 64 + wm + 4 * g;
  const int ncol0 = bn * 128 + wn + r;
#pragma unroll
  for (int mi = 0; mi < 2; ++mi) {
#pragma unroll
    for (int ni = 0; ni < 4; ++ni) {
      const int n = ncol0 + ni * 16;
      const float bv = bias[n];
      const int m0 = mrow0 + mi * 16;
      if (MODE == 2) {
#pragma unroll
        for (int r2 = 0; r2 < 4; ++r2)
          outf[(size_t)(m0 + r2) * N + n] = acc[mi][ni][r2] + bv;
      } else if (!isv) {
#pragma unroll
        for (int r2 = 0; r2 < 4; ++r2) {
          float v = acc[mi][ni][r2] + bv;
          v = fmaxf(v, 0.0f);
          outh[(size_t)(m0 + r2) * N + n] = f2bf(v);
        }
      } else {
        // v scattered in PV A-frag slot order:
        // addr = bh*131072 + hs*2048 + (t>>5)*32 + ((t>>2)&3)*8 + ((t>>4)&1)*4
        s16x4 o;
#pragma unroll
        for (int r2 = 0; r2 < 4; ++r2)
          o[r2] = (short)f2h(acc[mi][ni][r2] + bv);
        const int tloc = m0 & 2047;
        const size_t dst =
            (size_t)((m0 >> 11) * 16 + (n >> 6)) * (64 * 2048)
            + (size_t)(n & 63) * 2048
            + (size_t)((tloc >> 5) * 32 + ((tloc >> 2) & 3) * 8
                       + ((tloc >> 4) & 1) * 4);
        *(s16x4*)(outv + dst) = o;
      }
    }
  }
}

// ---------------- fused synthesizer attention, v4 ----------------
// v3 post-mortem: per-wave direct global reads = 20KB/wave-iter through
// L2 (1MB/CU working set kills L1), zero prefetch -> latency/L2-BW bound.
// v4: per-j 8KB w2t + 8KB vt superblocks staged in LDS (double-buffered,
// reg-staged T14 split: global loads issued at top of iter j for j+1,
// ds_write after compute). All 4 waves share the LDS copy (4x traffic cut).
// Pairwise-balanced qb remap: consecutive blockIdx sum to constant work.
__global__ __launch_bounds__(256, 4) void attn_kernel(
    const unsigned short* __restrict__ rh,   // bf16 [B*T][C] relu(h)
    const unsigned short* __restrict__ vt,   // fp16 slot-ordered v^T
    const unsigned short* __restrict__ w2t,  // bf16 [T][64] x log2e
    const float* __restrict__ b2s,           // [T] b2 x log2e
    unsigned short* __restrict__ yb) {       // bf16 [B*T][C]
  __shared__ unsigned short Wl[2][64 * 72];  // +8 pad: stride 144B
  __shared__ unsigned short Vl[2][64 * 72];
  const int tid = threadIdx.x;
  const int lane = tid & 63;
  const int wid = tid >> 6;              // 0..3
  const int g = lane >> 4, r = lane & 15;
  const int bid = blockIdx.x;
  const int kk = bid >> 1;
  const int bh = kk & 31;
  const int ps = kk >> 5;                // 0..15
  const int qb = (bid & 1) ? ps : (31 - ps);  // pairs sum to 31
  const int b = bh >> 4, nh = bh & 15;
  const int t0 = qb * 64;
  const int t = t0 + wid * 16 + r;       // this lane's q row

  // Q fragment (B-operand of S^T = w2t x rh)
  const unsigned short* qbase =
      rh + (size_t)(b * TT + t) * CC + nh * 64 + g * 8;
  const s16x8 qf0 = *(const s16x8*)(qbase);
  const s16x8 qf1 = *(const s16x8*)(qbase + 32);

  f32x4 yacc[4] = {};                    // [f] -> hs = f*16 + 4g + r2
  float lsum = 0.f;

  // staging geometry: thread t handles 32B of row (t>>2) at col (t&3)*16
  const int strow = tid >> 2;            // 0..63
  const int stc = (tid & 3) * 16;        // shorts
  const unsigned short* Wg = w2t + (size_t)strow * 64 + stc;
  const unsigned short* Vg =
      vt + (size_t)bh * (64 * 2048) + (size_t)strow * 2048 + stc;
  const int lidx = strow * 72 + stc;

  s16x8 wr0, wr1, vr0, vr1;
  if (qb > 0) {
    wr0 = *(const s16x8*)(Wg);
    wr1 = *(const s16x8*)(Wg + 8);
    vr0 = *(const s16x8*)(Vg);
    vr1 = *(const s16x8*)(Vg + 8);
    *(s16x8*)&Wl[0][lidx] = wr0;
    *(s16x8*)&Wl[0][lidx + 8] = wr1;
    *(s16x8*)&Vl[0][lidx] = vr0;
    *(s16x8*)&Vl[0][lidx + 8] = vr1;
  }

  // -------- main loop: qb full 64-s superblocks, unmasked --------
  for (int j = 0; j < qb; ++j) {
    __syncthreads();                     // buf[j&1] ready; buf[j&1^1] free
    const int cur = j & 1;
    const bool more = (j + 1 < qb);
    if (more) {                          // issue next-j loads early (T14)
      wr0 = *(const s16x8*)(Wg + (j + 1) * 4096);
      wr1 = *(const s16x8*)(Wg + (j + 1) * 4096 + 8);
      vr0 = *(const s16x8*)(Vg + (j + 1) * 64);
      vr1 = *(const s16x8*)(Vg + (j + 1) * 64 + 8);
    }
    unsigned pk[8];
#pragma unroll
    for (int sub = 0; sub < 4; ++sub) {
      const s16x8 af0 = *(const s16x8*)&Wl[cur][(sub * 16 + r) * 72 + g * 8];
      const s16x8 af1 =
          *(const s16x8*)&Wl[cur][(sub * 16 + r) * 72 + 32 + g * 8];
      f32x4 s = *(const f32x4*)(b2s + j * 64 + sub * 16 + 4 * g);
      s = mfma_bf16_16x16x32(af0, qf0, s);
      s = mfma_bf16_16x16x32(af1, qf1, s);
      const float p0 = ex2(s[0]), p1 = ex2(s[1]);
      const float p2 = ex2(s[2]), p3 = ex2(s[3]);
      lsum += (p0 + p1) + (p2 + p3);
      pk[sub * 2 + 0] = pkrtz(p0, p1);
      pk[sub * 2 + 1] = pkrtz(p2, p3);
    }
#pragma unroll
    for (int grp = 0; grp < 2; ++grp) {
      u32x4 pw = {pk[grp * 4 + 0], pk[grp * 4 + 1],
                  pk[grp * 4 + 2], pk[grp * 4 + 3]};
      const s16x8 pb = __builtin_bit_cast(s16x8, pw);
#pragma unroll
      for (int f = 0; f < 4; ++f) {
        const s16x8 vf =
            *(const s16x8*)&Vl[cur][(f * 16 + r) * 72 + grp * 32 + g * 8];
        yacc[f] = mfma_f16_16x16x32(vf, pb, yacc[f]);
      }
    }
    if (more) {                          // write j+1 into the other buffer
      const int nxt = cur ^ 1;
      *(s16x8*)&Wl[nxt][lidx] = wr0;
      *(s16x8*)&Wl[nxt][lidx + 8] = wr1;
      *(s16x8*)&Vl[nxt][lidx] = vr0;
      *(s16x8*)&Vl[nxt][lidx + 8] = vr1;
    }
  }

  // -------- diagonal tail: subs 0..wid at s = t0+16*sub, masked, global --
  const unsigned short* wbase = w2t + r * 64 + g * 8;
  const unsigned short* vbase =
      vt + (size_t)bh * (64 * 2048) + (size_t)r * 2048 + g * 8;
#pragma unroll
  for (int jj = 0; jj < 2; ++jj) {
    if (jj > (wid >> 1)) break;  // wave-uniform
    unsigned pk[4] = {0u, 0u, 0u, 0u};
#pragma unroll
    for (int h = 0; h < 2; ++h) {
      const int sub = 2 * jj + h;
      if (sub > wid) break;      // wave-uniform
      const int sbb = t0 + sub * 16;
      const unsigned short* wp = wbase + (size_t)sbb * 64;
      const s16x8 af0 = *(const s16x8*)(wp);
      const s16x8 af1 = *(const s16x8*)(wp + 32);
      f32x4 s = *(const f32x4*)(b2s + sbb + 4 * g);
      s = mfma_bf16_16x16x32(af0, qf0, s);
      s = mfma_bf16_16x16x32(af1, qf1, s);
      float p[4];
#pragma unroll
      for (int r2 = 0; r2 < 4; ++r2) {
        const int sc = sbb + 4 * g + r2;
        p[r2] = (sc <= t) ? ex2(s[r2]) : 0.f;
      }
      lsum += (p[0] + p[1]) + (p[2] + p[3]);
      pk[h * 2 + 0] = pkrtz(p[0], p[1]);
      pk[h * 2 + 1] = pkrtz(p[2], p[3]);
    }
    u32x4 pw = {pk[0], pk[1], pk[2], pk[3]};
    const s16x8 pb = __builtin_bit_cast(s16x8, pw);
    const int so = (2 * qb + jj) * 32;
#pragma unroll
    for (int f = 0; f < 4; ++f) {
      const s16x8 vf = *(const s16x8*)(vbase + (size_t)f * 32768 + so);
      yacc[f] = mfma_f16_16x16x32(vf, pb, yacc[f]);
    }
  }

  // -------- row sum + write --------
  lsum += __shfl_xor(lsum, 16);
  lsum += __shfl_xor(lsum, 32);
  const float inv = 1.0f / lsum;
  unsigned short* ob = yb + (size_t)(b * TT + t) * CC + nh * 64 + 4 * g;
#pragma unroll
  for (int f = 0; f < 4; ++f) {
    s16x4 o;
#pragma unroll
    for (int r2 = 0; r2 < 4; ++r2) o[r2] = (short)f2bf(yacc[f][r2] * inv);
    *(s16x4*)(ob + f * 16) = o;
  }
}

extern "C" void kernel_launch(void* const* d_in, const int* in_sizes, int n_in,
                              void* d_out, int out_size, void* d_ws,
                              size_t ws_size, hipStream_t stream) {
  const float* x      = (const float*)d_in[0];
  const float* w1_w   = (const float*)d_in[1];
  const float* w1_b   = (const float*)d_in[2];
  const float* w2     = (const float*)d_in[3];
  const float* b2     = (const float*)d_in[4];
  const float* v_w    = (const float*)d_in[5];
  const float* v_b    = (const float*)d_in[6];
  const float* proj_w = (const float*)d_in[7];
  const float* proj_b = (const float*)d_in[8];

  unsigned short* ws = (unsigned short*)d_ws;
  const size_t NX = (size_t)BB * TT * CC;  // 4194304
  const size_t NW = (size_t)CC * CC;       // 1048576
  unsigned short* xb  = ws;
  unsigned short* hb  = xb + NX;
  unsigned short* yb  = hb + NX;
  unsigned short* vt  = yb + NX;   // fp16 v, PV slot order
  unsigned short* w1b = vt + NX;   // w1b, vwb, pwb contiguous (cvtw)
  unsigned short* vwb = w1b + NW;
  unsigned short* pwb = vwb + NW;
  unsigned short* w2t = pwb + NW;  // bf16 [2048][64] x log2e
  float* b2s = (float*)(w2t + (size_t)TT * 64);  // [2048]

  cvt_kernel<<<4096, 256, 0, stream>>>(x, xb, (int)NX);
  cvtw_kernel<<<3072, 256, 0, stream>>>(w1_w, v_w, proj_w, w1b);
  w2t_kernel<<<512, 256, 0, stream>>>(w2, w2t, b2, b2s);

  gemm64_kernel<0><<<dim3(16, 64), 256, 0, stream>>>(
      xb, w1b, w1_b, vwb, v_b, hb, vt, nullptr);
  attn_kernel<<<1024, 256, 0, stream>>>(hb, vt, w2t, b2s, yb);
  gemm64_kernel<2><<<dim3(8, 64), 256, 0, stream>>>(
      yb, pwb, proj_b, nullptr, nullptr, nullptr, nullptr, (float*)d_out);
}